// Round 2
// baseline (368.088 us; speedup 1.0000x reference)
//
#include <hip/hip_runtime.h>
#include <hip/hip_fp16.h>

#define M_TOTAL 512
#define N_TOTAL 11008
#define K_TOTAL 4096
#define BM 128
#define BN 64
#define BK 64
#define LDK 72  // padded LDS K-stride (elements); 72*2=144 B, 16B-aligned rows

typedef short bf16x8 __attribute__((ext_vector_type(8)));
typedef float f32x4 __attribute__((ext_vector_type(4)));

// pack two fp32 into two bf16 (round-half-up) -> uint32 (f0 in low 16)
__device__ inline unsigned int pack2_bf16(float f0, float f1) {
    unsigned int u0 = __builtin_bit_cast(unsigned int, f0) + 0x8000u;
    unsigned int u1 = __builtin_bit_cast(unsigned int, f1) + 0x8000u;
    return (u0 >> 16) | (u1 & 0xFFFF0000u);
}

// Detect the delivered dtype of weight_norm: 0=f32, 1=f16, 2=bf16.
// All true norms lie in [0.01, 0.11]; wrong interpretations provably
// fall outside [0.005, 0.12] for at least one of 64 probed elements.
__global__ void detect_norm_dtype(const void* __restrict__ wn, int* __restrict__ mode_out) {
    if (threadIdx.x != 0 || blockIdx.x != 0) return;
    const unsigned short* u16 = (const unsigned short*)wn;
    const float* f32p = (const float*)wn;
    bool ok_bf16 = true, ok_f16 = true, ok_f32 = true;
    for (int i = 0; i < 64; ++i) {
        float vb = __builtin_bit_cast(float, (unsigned int)u16[i] << 16);
        if (!(vb > 0.005f && vb < 0.12f)) ok_bf16 = false;
        float vh = __half2float(__builtin_bit_cast(__half, u16[i]));
        if (!(vh > 0.005f && vh < 0.12f)) ok_f16 = false;
        float vf = f32p[i];
        if (!(vf > 0.005f && vf < 0.12f)) ok_f32 = false;
    }
    *mode_out = ok_bf16 ? 2 : (ok_f16 ? 1 : 0);
}

__global__ void __launch_bounds__(256)
l3b_gemm_kernel(const float* __restrict__ x, const int* __restrict__ wq,
                const void* __restrict__ wnorm, const float* __restrict__ bias,
                float* __restrict__ out, const int* __restrict__ mode_ptr)
{
    __shared__ unsigned short As[BM * LDK];  // [m][k], bf16 bits
    __shared__ unsigned short Bs[BN * LDK];  // [n][k], bf16 bits

    const int mode = *mode_ptr;

    const int tid  = threadIdx.x;
    const int m0   = blockIdx.y * BM;
    const int n0   = blockIdx.x * BN;

    const int wid  = tid >> 6;
    const int lane = tid & 63;
    const int quad = lane >> 4;
    const int lm   = lane & 15;
    const int wm   = (wid >> 1) * 64;  // wave m offset within tile
    const int wn   = (wid & 1) * 32;   // wave n offset within tile

    f32x4 acc[4][2];
#pragma unroll
    for (int i = 0; i < 4; ++i)
#pragma unroll
        for (int j = 0; j < 2; ++j) acc[i][j] = (f32x4){0.f, 0.f, 0.f, 0.f};

    // A staging: 128 rows x 64 cols fp32; thread covers (ar + 16p, ac..ac+3)
    const int ar = tid >> 4;
    const int ac = (tid & 15) * 4;

    // B staging: 64 n-rows x 2 k-groups = 128 groups; 2 threads/group (16 wts each)
    const int gin      = tid >> 1;   // group-in-tile 0..127
    const int half     = tid & 1;    // which 16 weights of the group
    const int bn_local = gin >> 1;   // 0..63
    const int bkg      = gin & 1;    // 0..1 (k-group within BK)

    for (int it = 0; it < K_TOTAL / BK; ++it) {
        const int k0 = it * BK;
        __syncthreads();  // protect previous iteration's LDS reads

        // ---- stage A: fp32 -> bf16(rhu) -> LDS [m][k]
#pragma unroll
        for (int p = 0; p < 8; ++p) {
            const int row = p * 16 + ar;
            const float4 v = *(const float4*)&x[(m0 + row) * K_TOTAL + k0 + ac];
            unsigned int p0 = pack2_bf16(v.x, v.y);
            unsigned int p1 = pack2_bf16(v.z, v.w);
            *(uint2*)&As[row * LDK + ac] = make_uint2(p0, p1);
        }

        // ---- stage B: decode 16 3-bit weights -> bf16 -> LDS [n][k]
        {
            const int g    = (n0 + bn_local) * (K_TOTAL / 32) + it * 2 + bkg;
            const int base = g * 12 + half * 6;
            const int2 w0 = *(const int2*)&wq[base];
            const int2 w1 = *(const int2*)&wq[base + 2];
            const int2 w2 = *(const int2*)&wq[base + 4];
            float nrm;
            if (mode == 0)      nrm = ((const float*)wnorm)[g];
            else if (mode == 1) nrm = __half2float(((const __half*)wnorm)[g]);
            else                nrm = __builtin_bit_cast(float,
                                    (unsigned int)((const unsigned short*)wnorm)[g] << 16);
            const float a = nrm * (2.0f / 7.0f);
            const float b = -nrm;
            const unsigned int bits0 =
                (unsigned)w0.x | ((unsigned)w0.y << 8) | ((unsigned)w1.x << 16);
            const unsigned int bits1 =
                (unsigned)w1.y | ((unsigned)w2.x << 8) | ((unsigned)w2.y << 16);
            unsigned int packs[8];
#pragma unroll
            for (int t3 = 0; t3 < 2; ++t3) {
                const unsigned int bits = t3 ? bits1 : bits0;
#pragma unroll
                for (int j = 0; j < 4; ++j) {
                    const float f0 = fmaf((float)((bits >> (6 * j)) & 7), a, b);
                    const float f1 = fmaf((float)((bits >> (6 * j + 3)) & 7), a, b);
                    packs[t3 * 4 + j] = pack2_bf16(f0, f1);
                }
            }
            unsigned int* dst =
                (unsigned int*)&Bs[bn_local * LDK + bkg * 32 + half * 16];
            *(uint4*)dst       = make_uint4(packs[0], packs[1], packs[2], packs[3]);
            *(uint4*)(dst + 4) = make_uint4(packs[4], packs[5], packs[6], packs[7]);
        }
        __syncthreads();

        // ---- MFMA: 2 k-steps of 32
#pragma unroll
        for (int ks = 0; ks < 2; ++ks) {
            const int kb = ks * 32 + quad * 8;
            bf16x8 aF[4], bF[2];
#pragma unroll
            for (int mi = 0; mi < 4; ++mi)
                aF[mi] = *(const bf16x8*)&As[(wm + mi * 16 + lm) * LDK + kb];
#pragma unroll
            for (int ni = 0; ni < 2; ++ni)
                bF[ni] = *(const bf16x8*)&Bs[(wn + ni * 16 + lm) * LDK + kb];
#pragma unroll
            for (int mi = 0; mi < 4; ++mi)
#pragma unroll
                for (int ni = 0; ni < 2; ++ni)
                    acc[mi][ni] = __builtin_amdgcn_mfma_f32_16x16x32_bf16(
                        aF[mi], bF[ni], acc[mi][ni], 0, 0, 0);
        }
    }

    // ---- epilogue: C/D layout col=lane&15, row=quad*4+reg
#pragma unroll
    for (int ni = 0; ni < 2; ++ni) {
        const int o  = n0 + wn + ni * 16 + lm;
        const float bv = bias[o];
#pragma unroll
        for (int mi = 0; mi < 4; ++mi) {
#pragma unroll
            for (int r = 0; r < 4; ++r) {
                const int m = m0 + wm + mi * 16 + quad * 4 + r;
                out[m * N_TOTAL + o] = acc[mi][ni][r] + bv;
            }
        }
    }
}

extern "C" void kernel_launch(void* const* d_in, const int* in_sizes, int n_in,
                              void* d_out, int out_size, void* d_ws, size_t ws_size,
                              hipStream_t stream) {
    const float* x    = (const float*)d_in[0];
    const int*   wq   = (const int*)d_in[1];
    const void*  wn   = d_in[2];
    const float* bias = (const float*)d_in[3];
    float* out = (float*)d_out;
    int* mode = (int*)d_ws;

    detect_norm_dtype<<<1, 64, 0, stream>>>(wn, mode);

    dim3 grid(N_TOTAL / BN, M_TOTAL / BM);  // 172 x 4
    l3b_gemm_kernel<<<grid, 256, 0, stream>>>(x, wq, wn, bias, out, mode);
}

// Round 3
// 292.084 us; speedup vs baseline: 1.2602x; 1.2602x over previous
//
#include <hip/hip_runtime.h>
#include <hip/hip_fp16.h>

#define M_TOTAL 512
#define N_TOTAL 11008
#define K_TOTAL 4096
#define BM 128
#define BN 64
#define BK 64
#define NT (K_TOTAL / BK)  // 64
#define LDK 72             // fallback kernel's padded stride

typedef short bf16x8 __attribute__((ext_vector_type(8)));
typedef float f32x4 __attribute__((ext_vector_type(4)));

// pack two fp32 into two bf16 (round-half-up) -> uint32 (f0 in low 16)
__device__ __forceinline__ unsigned int pack2_bf16(float f0, float f1) {
    unsigned int u0 = __builtin_bit_cast(unsigned int, f0) + 0x8000u;
    unsigned int u1 = __builtin_bit_cast(unsigned int, f1) + 0x8000u;
    return (u0 >> 16) | (u1 & 0xFFFF0000u);
}

// async global->LDS 16B DMA (LDS dest must be wave-uniform base + lane*16)
__device__ __forceinline__ void async_ld16(void* lds, const void* g) {
    __builtin_amdgcn_global_load_lds(
        (const __attribute__((address_space(1))) unsigned int*)g,
        (__attribute__((address_space(3))) unsigned int*)lds, 16, 0, 0);
}

// Detect delivered dtype of weight_norm: 0=f32, 1=f16, 2=bf16.
__global__ void detect_norm_dtype(const void* __restrict__ wn, int* __restrict__ mode_out) {
    if (threadIdx.x != 0 || blockIdx.x != 0) return;
    const unsigned short* u16 = (const unsigned short*)wn;
    const float* f32p = (const float*)wn;
    bool ok_bf16 = true, ok_f16 = true, ok_f32 = true;
    for (int i = 0; i < 64; ++i) {
        float vb = __builtin_bit_cast(float, (unsigned int)u16[i] << 16);
        if (!(vb > 0.005f && vb < 0.12f)) ok_bf16 = false;
        float vh = __half2float(__builtin_bit_cast(__half, u16[i]));
        if (!(vh > 0.005f && vh < 0.12f)) ok_f16 = false;
        float vf = f32p[i];
        if (!(vf > 0.005f && vf < 0.12f)) ok_f32 = false;
    }
    *mode_out = ok_bf16 ? 2 : (ok_f16 ? 1 : 0);
}

// one-shot x fp32 -> bf16 (exact element count: 512*4096 / 4 per thread / 256 = 2048 blocks)
__global__ void __launch_bounds__(256)
convert_x_kernel(const float* __restrict__ x, unsigned short* __restrict__ xb) {
    const int i = (blockIdx.x * 256 + threadIdx.x) * 4;
    const float4 v = *(const float4*)&x[i];
    *(uint2*)&xb[i] = make_uint2(pack2_bf16(v.x, v.y), pack2_bf16(v.z, v.w));
}

// ---------------- pipelined main kernel ----------------
__global__ void __launch_bounds__(256)
l3b_gemm_pipe(const unsigned short* __restrict__ xb, const int* __restrict__ wq,
              const void* __restrict__ wnorm, const float* __restrict__ bias,
              float* __restrict__ out, const int* __restrict__ mode_ptr)
{
    // XOR-swizzled, unpadded: row stride 64 el (128 B); 16-B chunk p of row r
    // holds logical chunk p ^ (r & 7).
    __shared__ unsigned short As[2][BM * 64];  // 16 KB x2
    __shared__ unsigned short Bs[2][BN * 64];  // 8 KB x2

    const int mode = *mode_ptr;
    const int tid  = threadIdx.x;
    const int m0   = blockIdx.x * BM;  // grid (4, 172): consecutive blocks share B-tile
    const int n0   = blockIdx.y * BN;

    const int wid  = tid >> 6;
    const int lane = tid & 63;
    const int quad = lane >> 4;
    const int lm   = lane & 15;
    const int wm   = (wid >> 1) * 64;
    const int wn   = (wid & 1) * 32;

    // A-DMA geometry: issue j covers rows wid*32+j*8 .. +8; lane -> (row, phys chunk)
    const int arow0 = wid * 32 + (lane >> 3);                 // + j*8
    const int acol  = ((lane & 7) ^ ((lane >> 3) & 7)) * 8;   // logical el col (swizzle on global side)
    const int aslot = (lane & 7) * 8;                         // physical el col in LDS

    // B decode geometry: 2 threads per 32-weight group
    const int gin      = tid >> 1;
    const int half     = tid & 1;
    const int bn_local = gin >> 1;  // 0..63
    const int bkg      = gin & 1;   // k-group within BK
    const int c0       = bkg * 4 + half * 2;  // first logical chunk this thread writes
    const int swz      = bn_local & 7;

    auto stageA = [&](int it, int buf) {
#pragma unroll
        for (int j = 0; j < 4; ++j) {
            const int row = arow0 + j * 8;
            async_ld16(&As[buf][(row << 6) + aslot],
                       &xb[(size_t)(m0 + row) * K_TOTAL + it * 64 + acol]);
        }
    };

    int rb[2][6];
    float rnorm[2];
    auto loadB = [&](int it, int p) {
        const int g    = (n0 + bn_local) * (K_TOTAL / 32) + it * 2 + bkg;
        const int base = g * 12 + half * 6;
        *(int2*)&rb[p][0] = *(const int2*)&wq[base];
        *(int2*)&rb[p][2] = *(const int2*)&wq[base + 2];
        *(int2*)&rb[p][4] = *(const int2*)&wq[base + 4];
        if (mode == 0)      rnorm[p] = ((const float*)wnorm)[g];
        else if (mode == 1) rnorm[p] = __half2float(((const __half*)wnorm)[g]);
        else                rnorm[p] = __builtin_bit_cast(float,
                               (unsigned int)((const unsigned short*)wnorm)[g] << 16);
    };

    auto decodeB = [&](int p, int buf) {
        const float a = rnorm[p] * (2.0f / 7.0f);
        const float b = -rnorm[p];
        const unsigned int bits0 =
            (unsigned)rb[p][0] | ((unsigned)rb[p][1] << 8) | ((unsigned)rb[p][2] << 16);
        const unsigned int bits1 =
            (unsigned)rb[p][3] | ((unsigned)rb[p][4] << 8) | ((unsigned)rb[p][5] << 16);
        unsigned int packs[8];
#pragma unroll
        for (int t3 = 0; t3 < 2; ++t3) {
            const unsigned int bits = t3 ? bits1 : bits0;
#pragma unroll
            for (int j = 0; j < 4; ++j) {
                const float f0 = fmaf((float)((bits >> (6 * j)) & 7), a, b);
                const float f1 = fmaf((float)((bits >> (6 * j + 3)) & 7), a, b);
                packs[t3 * 4 + j] = pack2_bf16(f0, f1);
            }
        }
        *(uint4*)&Bs[buf][(bn_local << 6) + ((c0 ^ swz) << 3)] =
            make_uint4(packs[0], packs[1], packs[2], packs[3]);
        *(uint4*)&Bs[buf][(bn_local << 6) + (((c0 + 1) ^ swz) << 3)] =
            make_uint4(packs[4], packs[5], packs[6], packs[7]);
    };

    f32x4 acc[4][2];
#pragma unroll
    for (int i = 0; i < 4; ++i)
#pragma unroll
        for (int j = 0; j < 2; ++j) acc[i][j] = (f32x4){0.f, 0.f, 0.f, 0.f};

    // prologue: stage tile 0, prefetch packed B for tile 1
    stageA(0, 0);
    loadB(0, 0);
    decodeB(0, 0);
    loadB(1, 1);
    __syncthreads();  // drains A-DMA(0) + LDS writes

    for (int it = 0; it < NT; ++it) {
        const int cur = it & 1, nxt = cur ^ 1;
        if (it + 1 < NT) {
            stageA(it + 1, nxt);          // async; drained by loop-end barrier
            decodeB((it + 1) & 1, nxt);   // regs loaded at it-1 (already drained)
        }
        if (it + 2 < NT) loadB(it + 2, it & 1);  // in flight across MFMA + barrier

        // MFMA on tile it from cur
#pragma unroll
        for (int ks = 0; ks < 2; ++ks) {
            const int cswz = (((ks * 4 + quad) ^ (lm & 7)) << 3);
            bf16x8 aF[4], bF[2];
#pragma unroll
            for (int mi = 0; mi < 4; ++mi)
                aF[mi] = *(const bf16x8*)&As[cur][((wm + mi * 16 + lm) << 6) + cswz];
#pragma unroll
            for (int ni = 0; ni < 2; ++ni)
                bF[ni] = *(const bf16x8*)&Bs[cur][((wn + ni * 16 + lm) << 6) + cswz];
#pragma unroll
            for (int mi = 0; mi < 4; ++mi)
#pragma unroll
                for (int ni = 0; ni < 2; ++ni)
                    acc[mi][ni] = __builtin_amdgcn_mfma_f32_16x16x32_bf16(
                        aF[mi], bF[ni], acc[mi][ni], 0, 0, 0);
        }
        __syncthreads();  // single barrier: drains DMA(it+1), B loads, LDS ops
    }

    // epilogue: C/D layout col=lane&15, row=quad*4+reg
#pragma unroll
    for (int ni = 0; ni < 2; ++ni) {
        const int o  = n0 + wn + ni * 16 + lm;
        const float bv = bias[o];
#pragma unroll
        for (int mi = 0; mi < 4; ++mi) {
#pragma unroll
            for (int r = 0; r < 4; ++r) {
                const int m = m0 + wm + mi * 16 + quad * 4 + r;
                out[m * N_TOTAL + o] = acc[mi][ni][r] + bv;
            }
        }
    }
}

// ---------------- fallback (r2 kernel) if ws too small ----------------
__global__ void __launch_bounds__(256)
l3b_gemm_kernel(const float* __restrict__ x, const int* __restrict__ wq,
                const void* __restrict__ wnorm, const float* __restrict__ bias,
                float* __restrict__ out, const int* __restrict__ mode_ptr)
{
    __shared__ unsigned short As[BM * LDK];
    __shared__ unsigned short Bs[BN * LDK];

    const int mode = *mode_ptr;
    const int tid  = threadIdx.x;
    const int m0   = blockIdx.y * BM;
    const int n0   = blockIdx.x * BN;
    const int wid  = tid >> 6;
    const int lane = tid & 63;
    const int quad = lane >> 4;
    const int lm   = lane & 15;
    const int wm   = (wid >> 1) * 64;
    const int wn   = (wid & 1) * 32;

    f32x4 acc[4][2];
#pragma unroll
    for (int i = 0; i < 4; ++i)
#pragma unroll
        for (int j = 0; j < 2; ++j) acc[i][j] = (f32x4){0.f, 0.f, 0.f, 0.f};

    const int ar = tid >> 4;
    const int ac = (tid & 15) * 4;
    const int gin      = tid >> 1;
    const int half     = tid & 1;
    const int bn_local = gin >> 1;
    const int bkg      = gin & 1;

    for (int it = 0; it < NT; ++it) {
        const int k0 = it * BK;
        __syncthreads();
#pragma unroll
        for (int p = 0; p < 8; ++p) {
            const int row = p * 16 + ar;
            const float4 v = *(const float4*)&x[(m0 + row) * K_TOTAL + k0 + ac];
            *(uint2*)&As[row * LDK + ac] =
                make_uint2(pack2_bf16(v.x, v.y), pack2_bf16(v.z, v.w));
        }
        {
            const int g    = (n0 + bn_local) * (K_TOTAL / 32) + it * 2 + bkg;
            const int base = g * 12 + half * 6;
            const int2 w0 = *(const int2*)&wq[base];
            const int2 w1 = *(const int2*)&wq[base + 2];
            const int2 w2 = *(const int2*)&wq[base + 4];
            float nrm;
            if (mode == 0)      nrm = ((const float*)wnorm)[g];
            else if (mode == 1) nrm = __half2float(((const __half*)wnorm)[g]);
            else                nrm = __builtin_bit_cast(float,
                                    (unsigned int)((const unsigned short*)wnorm)[g] << 16);
            const float a = nrm * (2.0f / 7.0f);
            const float b = -nrm;
            const unsigned int bits0 =
                (unsigned)w0.x | ((unsigned)w0.y << 8) | ((unsigned)w1.x << 16);
            const unsigned int bits1 =
                (unsigned)w1.y | ((unsigned)w2.x << 8) | ((unsigned)w2.y << 16);
            unsigned int packs[8];
#pragma unroll
            for (int t3 = 0; t3 < 2; ++t3) {
                const unsigned int bits = t3 ? bits1 : bits0;
#pragma unroll
                for (int j = 0; j < 4; ++j) {
                    const float f0 = fmaf((float)((bits >> (6 * j)) & 7), a, b);
                    const float f1 = fmaf((float)((bits >> (6 * j + 3)) & 7), a, b);
                    packs[t3 * 4 + j] = pack2_bf16(f0, f1);
                }
            }
            unsigned int* dst = (unsigned int*)&Bs[bn_local * LDK + bkg * 32 + half * 16];
            *(uint4*)dst       = make_uint4(packs[0], packs[1], packs[2], packs[3]);
            *(uint4*)(dst + 4) = make_uint4(packs[4], packs[5], packs[6], packs[7]);
        }
        __syncthreads();
#pragma unroll
        for (int ks = 0; ks < 2; ++ks) {
            const int kb = ks * 32 + quad * 8;
            bf16x8 aF[4], bF[2];
#pragma unroll
            for (int mi = 0; mi < 4; ++mi)
                aF[mi] = *(const bf16x8*)&As[(wm + mi * 16 + lm) * LDK + kb];
#pragma unroll
            for (int ni = 0; ni < 2; ++ni)
                bF[ni] = *(const bf16x8*)&Bs[(wn + ni * 16 + lm) * LDK + kb];
#pragma unroll
            for (int mi = 0; mi < 4; ++mi)
#pragma unroll
                for (int ni = 0; ni < 2; ++ni)
                    acc[mi][ni] = __builtin_amdgcn_mfma_f32_16x16x32_bf16(
                        aF[mi], bF[ni], acc[mi][ni], 0, 0, 0);
        }
    }
#pragma unroll
    for (int ni = 0; ni < 2; ++ni) {
        const int o  = n0 + wn + ni * 16 + lm;
        const float bv = bias[o];
#pragma unroll
        for (int mi = 0; mi < 4; ++mi)
#pragma unroll
            for (int r = 0; r < 4; ++r) {
                const int m = m0 + wm + mi * 16 + quad * 4 + r;
                out[m * N_TOTAL + o] = acc[mi][ni][r] + bv;
            }
    }
}

extern "C" void kernel_launch(void* const* d_in, const int* in_sizes, int n_in,
                              void* d_out, int out_size, void* d_ws, size_t ws_size,
                              hipStream_t stream) {
    const float* x    = (const float*)d_in[0];
    const int*   wq   = (const int*)d_in[1];
    const void*  wn   = d_in[2];
    const float* bias = (const float*)d_in[3];
    float* out = (float*)d_out;
    int* mode = (int*)d_ws;

    detect_norm_dtype<<<1, 64, 0, stream>>>(wn, mode);

    const size_t need = 256 + (size_t)M_TOTAL * K_TOTAL * 2;
    if (ws_size >= need) {
        unsigned short* xb = (unsigned short*)((char*)d_ws + 256);
        convert_x_kernel<<<(M_TOTAL * K_TOTAL / 4) / 256, 256, 0, stream>>>(x, xb);
        dim3 grid(M_TOTAL / BM, N_TOTAL / BN);  // (4, 172)
        l3b_gemm_pipe<<<grid, 256, 0, stream>>>(xb, wq, wn, bias, out, mode);
    } else {
        dim3 grid(N_TOTAL / BN, M_TOTAL / BM);  // (172, 4)
        l3b_gemm_kernel<<<grid, 256, 0, stream>>>(x, wq, wn, bias, out, mode);
    }
}

// Round 4
// 207.342 us; speedup vs baseline: 1.7753x; 1.4087x over previous
//
#include <hip/hip_runtime.h>
#include <hip/hip_fp16.h>

#define M_TOTAL 512
#define N_TOTAL 11008
#define K_TOTAL 4096
#define BM 128
#define BN 64
#define BK 64
#define NT (K_TOTAL / BK)  // 64
#define LDK 72             // fallback kernel's padded stride

typedef short bf16x8 __attribute__((ext_vector_type(8)));
typedef float f32x4 __attribute__((ext_vector_type(4)));

// pack two fp32 into two bf16 (round-half-up) -> uint32 (f0 in low 16)
__device__ __forceinline__ unsigned int pack2_bf16(float f0, float f1) {
    unsigned int u0 = __builtin_bit_cast(unsigned int, f0) + 0x8000u;
    unsigned int u1 = __builtin_bit_cast(unsigned int, f1) + 0x8000u;
    return (u0 >> 16) | (u1 & 0xFFFF0000u);
}

// async global->LDS 16B DMA (LDS dest must be wave-uniform base + lane*16)
__device__ __forceinline__ void async_ld16(void* lds, const void* g) {
    __builtin_amdgcn_global_load_lds(
        (const __attribute__((address_space(1))) unsigned int*)g,
        (__attribute__((address_space(3))) unsigned int*)lds, 16, 0, 0);
}

// Detect delivered dtype of weight_norm: 0=f32, 1=f16, 2=bf16.
__global__ void detect_norm_dtype(const void* __restrict__ wn, int* __restrict__ mode_out) {
    if (threadIdx.x != 0 || blockIdx.x != 0) return;
    const unsigned short* u16 = (const unsigned short*)wn;
    const float* f32p = (const float*)wn;
    bool ok_bf16 = true, ok_f16 = true, ok_f32 = true;
    for (int i = 0; i < 64; ++i) {
        float vb = __builtin_bit_cast(float, (unsigned int)u16[i] << 16);
        if (!(vb > 0.005f && vb < 0.12f)) ok_bf16 = false;
        float vh = __half2float(__builtin_bit_cast(__half, u16[i]));
        if (!(vh > 0.005f && vh < 0.12f)) ok_f16 = false;
        float vf = f32p[i];
        if (!(vf > 0.005f && vf < 0.12f)) ok_f32 = false;
    }
    *mode_out = ok_bf16 ? 2 : (ok_f16 ? 1 : 0);
}

// one-shot x fp32 -> bf16
__global__ void __launch_bounds__(256)
convert_x_kernel(const float* __restrict__ x, unsigned short* __restrict__ xb) {
    const int i = (blockIdx.x * 256 + threadIdx.x) * 4;
    const float4 v = *(const float4*)&x[i];
    *(uint2*)&xb[i] = make_uint2(pack2_bf16(v.x, v.y), pack2_bf16(v.z, v.w));
}

// ---------------- pipelined main kernel ----------------
__global__ void __launch_bounds__(256)
l3b_gemm_pipe(const unsigned short* __restrict__ xb, const int* __restrict__ wq,
              const void* __restrict__ wnorm, const float* __restrict__ bias,
              float* __restrict__ out, const int* __restrict__ mode_ptr)
{
    // XOR-swizzled, unpadded: row stride 64 el (128 B); 16-B chunk p of row r
    // holds logical chunk p ^ (r & 7).
    __shared__ unsigned short As[2][BM * 64];  // 16 KB x2
    __shared__ unsigned short Bs[2][BN * 64];  // 8 KB x2

    const int mode = *mode_ptr;
    const int tid  = threadIdx.x;
    const int m0   = blockIdx.x * BM;  // grid (4, 172)
    const int n0   = blockIdx.y * BN;

    const int wid  = tid >> 6;
    const int lane = tid & 63;
    const int quad = lane >> 4;
    const int lm   = lane & 15;
    const int wm   = (wid >> 1) * 64;
    const int wn   = (wid & 1) * 32;

    // A-DMA geometry
    const int arow0 = wid * 32 + (lane >> 3);                 // + j*8
    const int acol  = ((lane & 7) ^ ((lane >> 3) & 7)) * 8;   // swizzle on global side
    const int aslot = (lane & 7) * 8;                         // lane*16 B within wave's row span

    // B decode geometry: 2 threads per 32-weight group
    const int gin      = tid >> 1;
    const int half     = tid & 1;
    const int bn_local = gin >> 1;  // 0..63
    const int bkg      = gin & 1;   // k-group within BK
    const int c0       = bkg * 4 + half * 2;
    const int swz      = bn_local & 7;

    auto stageA = [&](int it, int buf) {
#pragma unroll
        for (int j = 0; j < 4; ++j) {
            const int row = arow0 + j * 8;
            async_ld16(&As[buf][(row << 6) + aslot],
                       &xb[(size_t)(m0 + row) * K_TOTAL + it * 64 + acol]);
        }
    };

    // NAMED double-buffer registers (no dynamic indexing -> no scratch)
    int2 w0a, w1a, w2a; float na;
    int2 w0b, w1b, w2b; float nb;

    auto loadNorm = [&](int g) -> float {
        if (mode == 0)      return ((const float*)wnorm)[g];
        else if (mode == 1) return __half2float(((const __half*)wnorm)[g]);
        else                return __builtin_bit_cast(float,
                               (unsigned int)((const unsigned short*)wnorm)[g] << 16);
    };
    auto loadB = [&](int it, int2& w0, int2& w1, int2& w2, float& nrm) {
        const int g    = (n0 + bn_local) * (K_TOTAL / 32) + it * 2 + bkg;
        const int base = g * 12 + half * 6;
        w0 = *(const int2*)&wq[base];
        w1 = *(const int2*)&wq[base + 2];
        w2 = *(const int2*)&wq[base + 4];
        nrm = loadNorm(g);
    };
    auto decodeB = [&](int2 w0, int2 w1, int2 w2, float nrm, int buf) {
        const float a = nrm * (2.0f / 7.0f);
        const float b = -nrm;
        const unsigned int bits0 =
            (unsigned)w0.x | ((unsigned)w0.y << 8) | ((unsigned)w1.x << 16);
        const unsigned int bits1 =
            (unsigned)w1.y | ((unsigned)w2.x << 8) | ((unsigned)w2.y << 16);
        unsigned int packs[8];
#pragma unroll
        for (int t3 = 0; t3 < 2; ++t3) {
            const unsigned int bits = t3 ? bits1 : bits0;
#pragma unroll
            for (int j = 0; j < 4; ++j) {
                const float f0 = fmaf((float)((bits >> (6 * j)) & 7), a, b);
                const float f1 = fmaf((float)((bits >> (6 * j + 3)) & 7), a, b);
                packs[t3 * 4 + j] = pack2_bf16(f0, f1);
            }
        }
        *(uint4*)&Bs[buf][(bn_local << 6) + ((c0 ^ swz) << 3)] =
            make_uint4(packs[0], packs[1], packs[2], packs[3]);
        *(uint4*)&Bs[buf][(bn_local << 6) + (((c0 + 1) ^ swz) << 3)] =
            make_uint4(packs[4], packs[5], packs[6], packs[7]);
    };

    f32x4 acc[4][2];
#pragma unroll
    for (int i = 0; i < 4; ++i)
#pragma unroll
        for (int j = 0; j < 2; ++j) acc[i][j] = (f32x4){0.f, 0.f, 0.f, 0.f};

    auto mfmaTile = [&](const unsigned short* Asb, const unsigned short* Bsb) {
#pragma unroll
        for (int ks = 0; ks < 2; ++ks) {
            const int cswz = (((ks * 4 + quad) ^ (lm & 7)) << 3);
            bf16x8 aF[4], bF[2];
#pragma unroll
            for (int mi = 0; mi < 4; ++mi)
                aF[mi] = *(const bf16x8*)&Asb[((wm + mi * 16 + lm) << 6) + cswz];
#pragma unroll
            for (int ni = 0; ni < 2; ++ni)
                bF[ni] = *(const bf16x8*)&Bsb[((wn + ni * 16 + lm) << 6) + cswz];
#pragma unroll
            for (int mi = 0; mi < 4; ++mi)
#pragma unroll
                for (int ni = 0; ni < 2; ++ni)
                    acc[mi][ni] = __builtin_amdgcn_mfma_f32_16x16x32_bf16(
                        aF[mi], bF[ni], acc[mi][ni], 0, 0, 0);
        }
    };

    // prologue: stage tile 0 into buf0 (setA), prefetch packed tile 1 (setB)
    stageA(0, 0);
    loadB(0, w0a, w1a, w2a, na);
    decodeB(w0a, w1a, w2a, na, 0);
    loadB(1, w0b, w1b, w2b, nb);
    __syncthreads();  // drains A-DMA(0) + LDS writes

    // manually unrolled x2: all register/buffer selects are compile-time
    for (int it = 0; it < NT; it += 2) {
        // ---- sub-iter 0: compute buf0 (tile it); prefetch tile it+1 -> buf1
        if (it + 1 < NT) {
            stageA(it + 1, 1);
            decodeB(w0b, w1b, w2b, nb, 1);   // setB holds tile it+1
        }
        if (it + 2 < NT) loadB(it + 2, w0a, w1a, w2a, na);
        mfmaTile(As[0], Bs[0]);
        __syncthreads();

        // ---- sub-iter 1: compute buf1 (tile it+1); prefetch tile it+2 -> buf0
        if (it + 2 < NT) {
            stageA(it + 2, 0);
            decodeB(w0a, w1a, w2a, na, 0);   // setA holds tile it+2
        }
        if (it + 3 < NT) loadB(it + 3, w0b, w1b, w2b, nb);
        mfmaTile(As[1], Bs[1]);
        __syncthreads();
    }

    // epilogue: C/D layout col=lane&15, row=quad*4+reg
#pragma unroll
    for (int ni = 0; ni < 2; ++ni) {
        const int o  = n0 + wn + ni * 16 + lm;
        const float bv = bias[o];
#pragma unroll
        for (int mi = 0; mi < 4; ++mi) {
#pragma unroll
            for (int r = 0; r < 4; ++r) {
                const int m = m0 + wm + mi * 16 + quad * 4 + r;
                out[m * N_TOTAL + o] = acc[mi][ni][r] + bv;
            }
        }
    }
}

// ---------------- fallback (r2 kernel) if ws too small ----------------
__global__ void __launch_bounds__(256)
l3b_gemm_kernel(const float* __restrict__ x, const int* __restrict__ wq,
                const void* __restrict__ wnorm, const float* __restrict__ bias,
                float* __restrict__ out, const int* __restrict__ mode_ptr)
{
    __shared__ unsigned short As[BM * LDK];
    __shared__ unsigned short Bs[BN * LDK];

    const int mode = *mode_ptr;
    const int tid  = threadIdx.x;
    const int m0   = blockIdx.y * BM;
    const int n0   = blockIdx.x * BN;
    const int wid  = tid >> 6;
    const int lane = tid & 63;
    const int quad = lane >> 4;
    const int lm   = lane & 15;
    const int wm   = (wid >> 1) * 64;
    const int wn   = (wid & 1) * 32;

    f32x4 acc[4][2];
#pragma unroll
    for (int i = 0; i < 4; ++i)
#pragma unroll
        for (int j = 0; j < 2; ++j) acc[i][j] = (f32x4){0.f, 0.f, 0.f, 0.f};

    const int ar = tid >> 4;
    const int ac = (tid & 15) * 4;
    const int gin      = tid >> 1;
    const int half     = tid & 1;
    const int bn_local = gin >> 1;
    const int bkg      = gin & 1;

    for (int it = 0; it < NT; ++it) {
        const int k0 = it * BK;
        __syncthreads();
#pragma unroll
        for (int p = 0; p < 8; ++p) {
            const int row = p * 16 + ar;
            const float4 v = *(const float4*)&x[(m0 + row) * K_TOTAL + k0 + ac];
            *(uint2*)&As[row * LDK + ac] =
                make_uint2(pack2_bf16(v.x, v.y), pack2_bf16(v.z, v.w));
        }
        {
            const int g    = (n0 + bn_local) * (K_TOTAL / 32) + it * 2 + bkg;
            const int base = g * 12 + half * 6;
            const int2 w0 = *(const int2*)&wq[base];
            const int2 w1 = *(const int2*)&wq[base + 2];
            const int2 w2 = *(const int2*)&wq[base + 4];
            float nrm;
            if (mode == 0)      nrm = ((const float*)wnorm)[g];
            else if (mode == 1) nrm = __half2float(((const __half*)wnorm)[g]);
            else                nrm = __builtin_bit_cast(float,
                                    (unsigned int)((const unsigned short*)wnorm)[g] << 16);
            const float a = nrm * (2.0f / 7.0f);
            const float b = -nrm;
            const unsigned int bits0 =
                (unsigned)w0.x | ((unsigned)w0.y << 8) | ((unsigned)w1.x << 16);
            const unsigned int bits1 =
                (unsigned)w1.y | ((unsigned)w2.x << 8) | ((unsigned)w2.y << 16);
            unsigned int packs[8];
#pragma unroll
            for (int t3 = 0; t3 < 2; ++t3) {
                const unsigned int bits = t3 ? bits1 : bits0;
#pragma unroll
                for (int j = 0; j < 4; ++j) {
                    const float f0 = fmaf((float)((bits >> (6 * j)) & 7), a, b);
                    const float f1 = fmaf((float)((bits >> (6 * j + 3)) & 7), a, b);
                    packs[t3 * 4 + j] = pack2_bf16(f0, f1);
                }
            }
            unsigned int* dst = (unsigned int*)&Bs[bn_local * LDK + bkg * 32 + half * 16];
            *(uint4*)dst       = make_uint4(packs[0], packs[1], packs[2], packs[3]);
            *(uint4*)(dst + 4) = make_uint4(packs[4], packs[5], packs[6], packs[7]);
        }
        __syncthreads();
#pragma unroll
        for (int ks = 0; ks < 2; ++ks) {
            const int kb = ks * 32 + quad * 8;
            bf16x8 aF[4], bF[2];
#pragma unroll
            for (int mi = 0; mi < 4; ++mi)
                aF[mi] = *(const bf16x8*)&As[(wm + mi * 16 + lm) * LDK + kb];
#pragma unroll
            for (int ni = 0; ni < 2; ++ni)
                bF[ni] = *(const bf16x8*)&Bs[(wn + ni * 16 + lm) * LDK + kb];
#pragma unroll
            for (int mi = 0; mi < 4; ++mi)
#pragma unroll
                for (int ni = 0; ni < 2; ++ni)
                    acc[mi][ni] = __builtin_amdgcn_mfma_f32_16x16x32_bf16(
                        aF[mi], bF[ni], acc[mi][ni], 0, 0, 0);
        }
    }
#pragma unroll
    for (int ni = 0; ni < 2; ++ni) {
        const int o  = n0 + wn + ni * 16 + lm;
        const float bv = bias[o];
#pragma unroll
        for (int mi = 0; mi < 4; ++mi)
#pragma unroll
            for (int r = 0; r < 4; ++r) {
                const int m = m0 + wm + mi * 16 + quad * 4 + r;
                out[m * N_TOTAL + o] = acc[mi][ni][r] + bv;
            }
    }
}

extern "C" void kernel_launch(void* const* d_in, const int* in_sizes, int n_in,
                              void* d_out, int out_size, void* d_ws, size_t ws_size,
                              hipStream_t stream) {
    const float* x    = (const float*)d_in[0];
    const int*   wq   = (const int*)d_in[1];
    const void*  wn   = d_in[2];
    const float* bias = (const float*)d_in[3];
    float* out = (float*)d_out;
    int* mode = (int*)d_ws;

    detect_norm_dtype<<<1, 64, 0, stream>>>(wn, mode);

    const size_t need = 256 + (size_t)M_TOTAL * K_TOTAL * 2;
    if (ws_size >= need) {
        unsigned short* xb = (unsigned short*)((char*)d_ws + 256);
        convert_x_kernel<<<(M_TOTAL * K_TOTAL / 4) / 256, 256, 0, stream>>>(x, xb);
        dim3 grid(M_TOTAL / BM, N_TOTAL / BN);  // (4, 172)
        l3b_gemm_pipe<<<grid, 256, 0, stream>>>(xb, wq, wn, bias, out, mode);
    } else {
        dim3 grid(N_TOTAL / BN, M_TOTAL / BM);  // (172, 4)
        l3b_gemm_kernel<<<grid, 256, 0, stream>>>(x, wq, wn, bias, out, mode);
    }
}